// Round 8
// baseline (180.119 us; speedup 1.0000x reference)
//
#include <hip/hip_runtime.h>

using u8  = unsigned char;
using u16 = unsigned short;
using u32 = unsigned int;
typedef __attribute__((ext_vector_type(8))) short short8;   // 8 bf16 (MFMA A/B frag)
typedef __attribute__((ext_vector_type(4))) float f32x4;    // MFMA C/D frag

#define QMIN 64    // screen: v >= 1.984375  (== (int)(v*32+0.5) >= 64)
#define CMAX 608   // fallback candidate max
#define RCAP 96    // ambiguous-band capacity (expected ~15-30, +10sd)
#define BERR 0.045f   // |v_true - v_stored|: mfma 0.0311 + bf16 half-ulp(v<4) 0.0078 = 0.039

__device__ __forceinline__ float bf2f(u16 u) {
    union { u32 i; float f; } c; c.i = ((u32)u) << 16; return c.f;
}
__device__ __forceinline__ u16 f2bf(float f) {
    union { float f; u32 i; } c; c.f = f;
    u32 u = c.i + 0x7FFFu + ((c.i >> 16) & 1u);   // RNE; inputs are finite
    return (u16)(u >> 16);
}

// ---------------------------------------------------------------------------
// Kernel 0: FRAGMENT-SWIZZLED bf16 operands + bf16 W_dec.  (unchanged)
// Swizzle: tile t=(mt*8+kt); lane l holds 8 bf16 at (row=16*mt+(l&15),
// k=32*kt+(l>>4)*8+j) at offset (t*64+l)*8.
// ---------------------------------------------------------------------------
__global__ __launch_bounds__(256) void prep_convert(const float* __restrict__ x,
                                                    const float* __restrict__ b_dec,
                                                    const float* __restrict__ W_enc,
                                                    const float* __restrict__ W_dec,
                                                    u16* __restrict__ Ap,
                                                    u16* __restrict__ Wb,
                                                    u16* __restrict__ Wd) {
    int i = blockIdx.x * 256 + threadIdx.x;     // grid = 2560 blocks exactly
    if (i < 131072) {                            // A: 256 mt x 8 kt tiles
        int lane = i & 63, t = i >> 6;
        int mt = t >> 3, kt = t & 7;
        int m = mt * 16 + (lane & 15);
        int k = kt * 32 + (lane >> 4) * 8;
        const float* xs = x + (size_t)m * 256 + k;
        const float* bd = b_dec + k;
        u32 o[4];
#pragma unroll
        for (int j = 0; j < 4; j++) {
            u16 lo = f2bf(xs[2*j]   - bd[2*j]);
            u16 hi = f2bf(xs[2*j+1] - bd[2*j+1]);
            o[j] = (u32)lo | ((u32)hi << 16);
        }
        *(uint4*)(Ap + (size_t)i * 8) = make_uint4(o[0], o[1], o[2], o[3]);
    } else if (i < 393216) {                     // W_enc: 512 nt x 8 kt tiles
        int j0 = i - 131072;
        int lane = j0 & 63, t = j0 >> 6;
        int nt = t >> 3, kt = t & 7;
        int n = nt * 16 + (lane & 15);
        int k = kt * 32 + (lane >> 4) * 8;
        const float* ws = W_enc + (size_t)n * 256 + k;
        u32 o[4];
#pragma unroll
        for (int j = 0; j < 4; j++) {
            u16 lo = f2bf(ws[2*j]);
            u16 hi = f2bf(ws[2*j+1]);
            o[j] = (u32)lo | ((u32)hi << 16);
        }
        *(uint4*)(Wb + (size_t)j0 * 8) = make_uint4(o[0], o[1], o[2], o[3]);
    } else {                                     // W_dec: plain bf16, 8/thread
        int j0 = i - 393216;
        const float* ws = W_dec + (size_t)j0 * 8;
        u32 o[4];
#pragma unroll
        for (int j = 0; j < 4; j++) {
            u16 lo = f2bf(ws[2*j]);
            u16 hi = f2bf(ws[2*j+1]);
            o[j] = (u32)lo | ((u32)hi << 16);
        }
        *(uint4*)(Wd + (size_t)j0 * 8) = make_uint4(o[0], o[1], o[2], o[3]);
    }
}

// ---------------------------------------------------------------------------
// Kernel 1 (v8): PURE GEMM + bias fold. [R7 validated: pure loop -> encode
// ~22us (out of top-5). R3-R5 lesson: divergent emission in the GEMM loop
// poisons the load pipeline -> never again.]
// C = bf16(ac + b_enc[col]) — select no longer reads b_enc per value.
// Operand SWAP: acc = mfma(b_frag, a_frag): D row=(lane>>4)*4+reg -> W col,
// D col=lane&15 -> x row. Lane: 4 consecutive cols of one row -> one uint2
// store to row-major C[4096][8192] bf16 (64 MB).
// Wave = 16 cols x 512 rows, 32 chunks of 16 rows; aE/aO named double
// buffer (static indices only). B strip = 8 short8 = 32 VGPR, loaded once.
// launch_bounds(512,4) = 4 waves/SIMD; grid 512 = exact fill.
// XCD: id%8=c -> cols c*1024..+1023: W 512KB + A 2MB fits 4MB XCD L2.
// ---------------------------------------------------------------------------
__global__ __launch_bounds__(512, 4) void encode_gemm(const u16* __restrict__ A,
                                                      const u16* __restrict__ W,
                                                      const float* __restrict__ b_enc,
                                                      u16* __restrict__ C) {
    const int tid  = threadIdx.x;
    const int lane = tid & 63;
    const int wave = tid >> 6;          // 0..7
    const int g16  = lane >> 4;
    const int l16  = lane & 15;

    const int id = blockIdx.x;          // 512 blocks (2 per CU)
    const int c  = id & 7, j = id >> 3; // c = XCD
    const int bx = c * 8 + (j & 7);     // col-block 0..63 (128 cols)
    const int rg = j >> 3;              // row-group 0..7 (512 rows)

    const int n0  = bx * 128 + wave * 16;   // wave's 16-col strip
    const int nt0 = bx * 8 + wave;          // wave's n-tile (0..511)
    const int mtb = rg * 32;                // first m-tile of row group

    // ---- B strip in registers, loaded once: 8 x short8 = 32 VGPR ----------
    short8 b[8];
    const u16* pW = W + (size_t)nt0 * 4096 + lane * 8;
#pragma unroll
    for (int kt = 0; kt < 8; kt++)
        b[kt] = *(const short8*)(pW + kt * 512);

    // bias for this lane's 4 output cols (folded into C)
    const float4 bq = *(const float4*)(b_enc + n0 + g16 * 4);

    const u16* pA = A + (size_t)mtb * 4096 + lane * 8;       // per-lane A base
    u16* pC = C + ((size_t)(mtb * 16 + l16) * 8192 + n0 + g16 * 4);

    short8 aE[8], aO[8];
#pragma unroll
    for (int kt = 0; kt < 8; kt++) aE[kt] = *(const short8*)(pA + kt * 512);

    for (int it = 0; it < 16; it++) {
        // prefetch odd chunk (loads issue before MFMA block -> hidden)
#pragma unroll
        for (int kt = 0; kt < 8; kt++) aO[kt] = *(const short8*)(pA + 4096 + kt * 512);
        {
            f32x4 ac = {0.f, 0.f, 0.f, 0.f};
#pragma unroll
            for (int kt = 0; kt < 8; kt++)
                ac = __builtin_amdgcn_mfma_f32_16x16x32_bf16(b[kt], aE[kt], ac, 0, 0, 0);
            u32 lo = (u32)f2bf(ac[0] + bq.x) | ((u32)f2bf(ac[1] + bq.y) << 16);
            u32 hi = (u32)f2bf(ac[2] + bq.z) | ((u32)f2bf(ac[3] + bq.w) << 16);
            *(uint2*)pC = make_uint2(lo, hi);    // unconditional, full-exec
        }
        pC += 16 * 8192;
        // prefetch next even chunk (clamped duplicate on final iter)
        const u16* pA2 = pA + (it == 15 ? 4096 : 8192);
#pragma unroll
        for (int kt = 0; kt < 8; kt++) aE[kt] = *(const short8*)(pA2 + kt * 512);
        {
            f32x4 ac = {0.f, 0.f, 0.f, 0.f};
#pragma unroll
            for (int kt = 0; kt < 8; kt++)
                ac = __builtin_amdgcn_mfma_f32_16x16x32_bf16(b[kt], aO[kt], ac, 0, 0, 0);
            u32 lo = (u32)f2bf(ac[0] + bq.x) | ((u32)f2bf(ac[1] + bq.y) << 16);
            u32 hi = (u32)f2bf(ac[2] + bq.z) | ((u32)f2bf(ac[3] + bq.w) << 16);
            *(uint2*)pC = make_uint2(lo, hi);
        }
        pC += 16 * 8192;
        pA += 8192;
    }
}

// ---------------------------------------------------------------------------
// Kernel 2 (v8): [R7 lesson: certain-refine (~100 MB W_enc + f64 VALU) only
// polishes VALUES of already-selected cols; set correctness needs band
// refine only. Dropped — certain z err <= 0.039 (R0-R5 shipped 0.031-order
// and passed); v>=4 still force-refined exactly. Also: C unpacked ONCE to
// v[32] regs (no b_enc loads — bias folded in C); s_sae stride-17 padding
// kills the 2.07M LDS bank conflicts in exact_col.]
// Per row: read C row (4 coalesced 16B bursts/thread) -> q-hist brackets T
// -> certain-in / ambiguous band -> fp64 band refine (exact ordering) ->
// decode with bf16 W_dec. Exact streaming fallback if screen invalid.
// ---------------------------------------------------------------------------
__global__ __launch_bounds__(256) void select_decode(const u16* __restrict__ C,
                                                     const float* __restrict__ x,
                                                     const float* __restrict__ W_enc,
                                                     const float* __restrict__ b_enc,
                                                     const u16* __restrict__ Wd,
                                                     const float* __restrict__ b_dec,
                                                     float* __restrict__ out) {
    const int r    = (blockIdx.x & 7) * 512 + (blockIdx.x >> 3);   // XCD-grouped
    const int tid  = threadIdx.x;
    const int lane = tid & 63;
    const int wave = tid >> 6;
    const int grp  = tid >> 4;     // 16 groups of 16 lanes
    const int l16  = tid & 15;

    __shared__ float s_sae[272];   // stride-17 padded: idx = k + (k>>4)
    __shared__ u32   hist[256];
    __shared__ int   wtot[4];
    __shared__ int   s_t32;
    __shared__ u32   s_c1, s_namb, s_nref;
    __shared__ int   cidx[CMAX];    // fallback only
    __shared__ float cval[CMAX];    // fallback only
    __shared__ short ridx[RCAP];    // band: column indices
    __shared__ float rex[RCAP];
    __shared__ float sel_val[32];
    __shared__ int   sel_idx[32];

    s_sae[tid + (tid >> 4)] = x[(size_t)r * 256 + tid] - b_dec[tid];
    hist[tid] = 0;
    if (tid == 0) { s_t32 = -1; s_c1 = 0; s_namb = 0; s_nref = 0; }
    if (tid < 32) { sel_val[tid] = 0.f; sel_idx[tid] = 0; }
    __syncthreads();

    auto find_t32 = [&]() {
        int c = (int)hist[tid];
        int s = c;
#pragma unroll
        for (int off = 1; off < 64; off <<= 1) {
            int v = __shfl_down(s, off);
            if (lane + off < 64) s += v;
        }
        if (lane == 0) wtot[wave] = s;
        __syncthreads();
        int hisum = 0;
        for (int ww = wave + 1; ww < 4; ww++) hisum += wtot[ww];
        int S = s + hisum;
        if (S >= 32 && (S - c) < 32) s_t32 = tid;   // unique transition bin
        __syncthreads();
    };
    auto exact_col = [&](int col) -> double {
        const float4* wr = (const float4*)(W_enc + (size_t)col * 256 + l16 * 16);
        double s = 0.0;
#pragma unroll
        for (int u = 0; u < 4; u++) {
            float4 wv = wr[u];
            const float* sp = &s_sae[l16 * 17 + u * 4];   // padded, conflict-free
            s += (double)wv.x * (double)sp[0] + (double)wv.y * (double)sp[1]
               + (double)wv.z * (double)sp[2] + (double)wv.w * (double)sp[3];
        }
#pragma unroll
        for (int off = 8; off; off >>= 1) s += __shfl_down(s, off, 16);
        return s;
    };

    // --- load C row once into v[32] registers (coalesced, bias pre-folded) --
    float v[32];
#pragma unroll
    for (int u = 0; u < 4; u++) {
        uint4 rv = *(const uint4*)(C + (size_t)r * 8192 + u * 2048 + tid * 8);
        u32 w0 = rv.x, w1 = rv.y, w2 = rv.z, w3 = rv.w;
        v[u*8+0] = bf2f((u16)(w0 & 0xFFFFu)); v[u*8+1] = bf2f((u16)(w0 >> 16));
        v[u*8+2] = bf2f((u16)(w1 & 0xFFFFu)); v[u*8+3] = bf2f((u16)(w1 >> 16));
        v[u*8+4] = bf2f((u16)(w2 & 0xFFFFu)); v[u*8+5] = bf2f((u16)(w2 >> 16));
        v[u*8+6] = bf2f((u16)(w3 & 0xFFFFu)); v[u*8+7] = bf2f((u16)(w3 >> 16));
    }

    // --- pass 1: histogram values >= screen ---------------------------------
#pragma unroll
    for (int e = 0; e < 32; e++) {
        float vv = v[e];
        if (vv >= 1.984375f) {
            int q = (int)(vv * 32.f + 0.5f); if (q > 255) q = 255;
            atomicAdd(&hist[q], 1u);
        }
    }
    __syncthreads();
    find_t32();

    // t32 >= 67 <=> Tlo-2B >= 1.984 -> non-screened values certainly out
    const bool fb_pre = (s_t32 < 67);

    if (!fb_pre) {
        const float Thi = (s_t32 + 0.5f) * 0.03125f;
        const float Tlo = (s_t32 - 0.5f) * 0.03125f;
#pragma unroll
        for (int e = 0; e < 32; e++) {
            float vv = v[e];
            int col = (e >> 3) * 2048 + tid * 8 + (e & 7);
            bool vbig = (vv >= 4.0f);          // bf16 ulp grows: force refine
            if (!vbig && vv > Thi + 2.f * BERR) {      // certainly in top-32
                u32 p = atomicAdd(&s_c1, 1u);
                if (p < 32) { sel_val[p] = vv; sel_idx[p] = col; }
            } else if (vbig || vv >= Tlo - 2.f * BERR) {   // ambiguous band
                u32 p = atomicAdd(&s_namb, 1u);
                if (p < RCAP) ridx[p] = (short)col;
            }
        }
    }
    __syncthreads();
    const int c1 = (int)s_c1, namb = (int)s_namb;
    const bool fb = fb_pre || (namb > RCAP) || (c1 > 31);

    if (!fb) {
        // --- fp64 refine of ambiguous band: 2 per 16-lane group per pass ----
        for (int t0 = 0; t0 < namb; t0 += 32) {
            int cA = t0 + grp, cB = t0 + grp + 16;
            if (cA < namb) {
                int iA = (int)ridx[cA];
                double s = exact_col(iA);
                if (l16 == 0) {
                    float f = (float)(s + (double)b_enc[iA]);
                    rex[cA] = f > 0.f ? f : 0.f;
                }
            }
            if (cB < namb) {
                int iB = (int)ridx[cB];
                double s = exact_col(iB);
                if (l16 == 0) {
                    float f = (float)(s + (double)b_enc[iB]);
                    rex[cB] = f > 0.f ? f : 0.f;
                }
            }
        }
        __syncthreads();

        // --- top (32-c1) of band by (exact desc, idx asc) -------------------
        const int need = 32 - c1;
        for (int k = tid; k < namb; k += 256) {
            float vi = rex[k];
            int   ii = (int)ridx[k];
            int rank = 0;
            for (int j = 0; j < namb; j++) {
                float vj = rex[j];
                rank += (vj > vi) || (vj == vi && (int)ridx[j] < ii);
            }
            if (rank < need) { sel_val[c1 + rank] = vi; sel_idx[c1 + rank] = ii; }
        }
        __syncthreads();
    } else {
        // --- exact streaming fallback over all 8192 cols (never expected) ---
        hist[tid] = 0;
        if (tid == 0) { s_t32 = -1; s_nref = 0; }
        __syncthreads();
        for (int it = 0; it < 512; it++) {
            int col = it * 16 + grp;
            double s = exact_col(col);
            if (l16 == 0) {
                float f = (float)(s + (double)b_enc[col]);
                f = f > 0.f ? f : 0.f;
                int q = (int)(f * 32.f + 0.5f); if (q > 255) q = 255;
                if (q >= 1) atomicAdd(&hist[q], 1u);
            }
        }
        __syncthreads();
        find_t32();
        int qlo = s_t32 >= 3 ? s_t32 - 2 : 1;
        for (int pass = 0; pass < 2; pass++) {
            for (int it = 0; it < 512; it++) {
                int col = it * 16 + grp;
                double s = exact_col(col);
                if (l16 == 0) {
                    float f = (float)(s + (double)b_enc[col]);
                    f = f > 0.f ? f : 0.f;
                    int q = (int)(f * 32.f + 0.5f); if (q > 255) q = 255;
                    if (q >= qlo) {
                        u32 p = atomicAdd(&s_nref, 1u);
                        if (p < CMAX) { cidx[p] = col; cval[p] = f; }
                    }
                }
            }
            __syncthreads();
            if ((int)s_nref <= CMAX) break;
            if (tid == 0) s_nref = 0;
            qlo = s_t32 > 0 ? s_t32 : 1;
            __syncthreads();
        }
        int nf = (int)s_nref; if (nf > CMAX) nf = CMAX;
        for (int k = tid; k < nf; k += 256) {
            float vi = cval[k]; int ii = cidx[k]; int rank = 0;
            for (int j = 0; j < nf; j++)
                rank += (cval[j] > vi) || (cval[j] == vi && cidx[j] < ii);
            if (rank < 32) { sel_val[rank] = vi; sel_idx[rank] = ii; }
        }
        __syncthreads();
    }

    // --- decode: out[r] = b_dec + sum_k z_k * bf16(W_dec)[idx_k] ------------
    u16 wv[32];
#pragma unroll
    for (int k = 0; k < 32; k++)
        wv[k] = Wd[(size_t)sel_idx[k] * 256 + tid];   // 32 independent loads
    float acc = b_dec[tid];
#pragma unroll
    for (int k = 0; k < 32; k++)
        acc += sel_val[k] * bf2f(wv[k]);
    out[(size_t)r * 256 + tid] = acc;
}

// ---------------------------------------------------------------------------
// ws layout (74 MB; ws_size 256 MB):
//   C 64 MB (bf16 [4096][8192], bias-folded, fully overwritten) |
//   Ap 2 MB | Wb 4 MB | Wd 4 MB
// ---------------------------------------------------------------------------
extern "C" void kernel_launch(void* const* d_in, const int* in_sizes, int n_in,
                              void* d_out, int out_size, void* d_ws, size_t ws_size,
                              hipStream_t stream) {
    const float* x     = (const float*)d_in[0];   // [4096,256] f32
    const float* W_enc = (const float*)d_in[1];   // [8192,256] f32
    const float* b_enc = (const float*)d_in[2];   // [8192]     f32
    const float* W_dec = (const float*)d_in[3];   // [8192,256] f32
    const float* b_dec = (const float*)d_in[4];   // [256]      f32
    float* out = (float*)d_out;                   // [4096,256] f32

    u16* C  = (u16*)d_ws;                         // 64 MB pre_acts+bias bf16
    u16* Ap = C  + (size_t)4096 * 8192;           // 2 MB swizzled bf16(x-b_dec)
    u16* Wb = Ap + (size_t)4096 * 256;            // 4 MB swizzled bf16(W_enc)
    u16* Wd = Wb + (size_t)8192 * 256;            // 4 MB bf16(W_dec)

    prep_convert<<<2560, 256, 0, stream>>>(x, b_dec, W_enc, W_dec, Ap, Wb, Wd);
    encode_gemm<<<512, 512, 0, stream>>>(Ap, Wb, b_enc, C);
    select_decode<<<4096, 256, 0, stream>>>(C, x, W_enc, b_enc, Wd, b_dec, out);
}

// Round 9
// 148.316 us; speedup vs baseline: 1.2144x; 1.2144x over previous
//
#include <hip/hip_runtime.h>

using u8  = unsigned char;
using u16 = unsigned short;
using u32 = unsigned int;
typedef __attribute__((ext_vector_type(8))) short short8;   // 8 bf16 (MFMA A/B frag)
typedef __attribute__((ext_vector_type(4))) float f32x4;    // MFMA C/D frag

#define SCAP 96     // per-row global spill capacity (expected ~4/row, hot ~30)
#define CMAX 608    // per-row candidate max (m_all <= ~500 at +7sd)
#define RCAP 96     // ambiguous-band capacity (expected ~25, +10sd)
#define BERR 0.045f // |v_true - v_list|: mfma bound 0.0311 + 2^-16 fixed-point
#define OVCAP 256   // per-block LDS overflow list (expected ~31, +6sd ~65)

__device__ __forceinline__ float bf2f(u16 u) {
    union { u32 i; float f; } c; c.i = ((u32)u) << 16; return c.f;
}
__device__ __forceinline__ u16 f2bf(float f) {
    union { float f; u32 i; } c; c.f = f;
    u32 u = c.i + 0x7FFFu + ((c.i >> 16) & 1u);   // RNE; inputs are finite
    return (u16)(u >> 16);
}

// entry: (n << 19) | fixed19, fixed19 = floor(v*65536) (sat 0x7FFFF) >= 130088
// for valid v >= 1.984375 -> 0 is a safe empty sentinel. Saturated -> refine.

// ---------------------------------------------------------------------------
// Kernel 0: FRAGMENT-SWIZZLED bf16 operands + bf16 W_dec + zero cnt.
// Swizzle: tile t=(mt*8+kt); lane l holds 8 bf16 at (row=16*mt+(l&15),
// k=32*kt+(l>>4)*8+j) at offset (t*64+l)*8.  (no seg zeroing needed: encode
// writes every seg cell unconditionally.)
// ---------------------------------------------------------------------------
__global__ __launch_bounds__(256) void prep_convert(const float* __restrict__ x,
                                                    const float* __restrict__ b_dec,
                                                    const float* __restrict__ W_enc,
                                                    const float* __restrict__ W_dec,
                                                    u16* __restrict__ Ap,
                                                    u16* __restrict__ Wb,
                                                    u16* __restrict__ Wd,
                                                    u32* __restrict__ cnt) {
    int i = blockIdx.x * 256 + threadIdx.x;     // grid = 2576 blocks exactly
    if (i < 131072) {                            // A: 256 mt x 8 kt tiles
        int lane = i & 63, t = i >> 6;
        int mt = t >> 3, kt = t & 7;
        int m = mt * 16 + (lane & 15);
        int k = kt * 32 + (lane >> 4) * 8;
        const float* xs = x + (size_t)m * 256 + k;
        const float* bd = b_dec + k;
        u32 o[4];
#pragma unroll
        for (int j = 0; j < 4; j++) {
            u16 lo = f2bf(xs[2*j]   - bd[2*j]);
            u16 hi = f2bf(xs[2*j+1] - bd[2*j+1]);
            o[j] = (u32)lo | ((u32)hi << 16);
        }
        *(uint4*)(Ap + (size_t)i * 8) = make_uint4(o[0], o[1], o[2], o[3]);
    } else if (i < 393216) {                     // W_enc: 512 nt x 8 kt tiles
        int j0 = i - 131072;
        int lane = j0 & 63, t = j0 >> 6;
        int nt = t >> 3, kt = t & 7;
        int n = nt * 16 + (lane & 15);
        int k = kt * 32 + (lane >> 4) * 8;
        const float* ws = W_enc + (size_t)n * 256 + k;
        u32 o[4];
#pragma unroll
        for (int j = 0; j < 4; j++) {
            u16 lo = f2bf(ws[2*j]);
            u16 hi = f2bf(ws[2*j+1]);
            o[j] = (u32)lo | ((u32)hi << 16);
        }
        *(uint4*)(Wb + (size_t)j0 * 8) = make_uint4(o[0], o[1], o[2], o[3]);
    } else if (i < 655360) {                     // W_dec: plain bf16, 8/thread
        int j0 = i - 393216;
        const float* ws = W_dec + (size_t)j0 * 8;
        u32 o[4];
#pragma unroll
        for (int j = 0; j < 4; j++) {
            u16 lo = f2bf(ws[2*j]);
            u16 hi = f2bf(ws[2*j+1]);
            o[j] = (u32)lo | ((u32)hi << 16);
        }
        *(uint4*)(Wd + (size_t)j0 * 8) = make_uint4(o[0], o[1], o[2], o[3]);
    } else {                                     // zero spill counters
        int j0 = i - 655360;
        if (j0 < 4096) cnt[j0] = 0;
    }
}

// ---------------------------------------------------------------------------
// Kernel 1 (v9): PURE-vmcnt GEMM + LDS-domain emission.
// [R7/R8 lesson: pure GEMM = 22us, but full-C-rescan select = 57us (latency-
//  bound row scan). R3-R5 lesson: global emission in-loop -> variable vmcnt
//  -> drain -> 35-51us. R5 lesson: fragile codegen demoted B regs (FETCH
//  10GB, VGPR 44).]
// v9 = v7's exact loop (dbuf A, reg B, swapped mfma) with the C STORE
// DELETED; emission per chunk goes to wave-private LDS cells (LDS atomics =
// lgkmcnt domain -> the global-load vmcnt pipeline stays exactly countable;
// loop body has ZERO global stores/atomics). Overflow -> block LDS list.
// Epilogue (1 barrier): unconditional uint2 seg write per cell (0-filled ->
// no pre-zero), LDS overflow flushed to global spill; if the LDS list
// itself overflowed (never expected), poison cnt[] -> select falls back
// exact for those rows. seg = [4096 rows][512 cells][2] u32 (R5 layout).
// LDS 50.3 KB -> 2 blocks/CU at (512,4) = 4 waves/SIMD.
// XCD: id%8=c -> cols c*1024..+1023: W 512KB + A 2MB fits 4MB XCD L2.
// ---------------------------------------------------------------------------
__global__ __launch_bounds__(512, 4) void encode_gemm(const u16* __restrict__ A,
                                                      const u16* __restrict__ W,
                                                      const float* __restrict__ b_enc,
                                                      u32* __restrict__ cnt,
                                                      u32* __restrict__ seg,
                                                      u32* __restrict__ spill) {
    const int tid  = threadIdx.x;
    const int lane = tid & 63;
    const int wave = tid >> 6;          // 0..7
    const int g16  = lane >> 4;
    const int l16  = lane & 15;

    const int id = blockIdx.x;          // 512 blocks (2 per CU)
    const int c  = id & 7, j = id >> 3; // c = XCD
    const int bx = c * 8 + (j & 7);     // col-block 0..63 (128 cols)
    const int rg = j >> 3;              // row-group 0..7 (512 rows)

    const int n0  = bx * 128 + wave * 16;   // wave's 16-col strip
    const int nt0 = bx * 8 + wave;          // wave's n-tile (0..511)
    const int mtb = rg * 32;                // first m-tile of row group

    __shared__ u32 cell[512][8][2];     // 32 KB wave-private candidate cells
    __shared__ u32 lcnt[512][8];        // 16 KB per-cell counters
    __shared__ u32 ovr[OVCAP];          // 1 KB overflow rows (global row id)
    __shared__ u32 ove[OVCAP];          // 1 KB overflow entries
    __shared__ u32 s_ovn;

    {   // init counters (8 per thread) — covered by the syncthreads below
#pragma unroll
        for (int s = 0; s < 8; s++) {
            int k = s * 512 + tid;
            lcnt[k >> 3][k & 7] = 0;
        }
        if (tid == 0) s_ovn = 0;
    }

    // ---- B strip in registers, loaded once: 8 x short8 = 32 VGPR ----------
    short8 b[8];
    const u16* pW = W + (size_t)nt0 * 4096 + lane * 8;
#pragma unroll
    for (int kt = 0; kt < 8; kt++)
        b[kt] = *(const short8*)(pW + kt * 512);

    const float4 bq = *(const float4*)(b_enc + n0 + g16 * 4);
    const float bqa0 = bq.x, bqa1 = bq.y, bqa2 = bq.z, bqa3 = bq.w;

    const u16* pA = A + (size_t)mtb * 4096 + lane * 8;       // per-lane A base

    __syncthreads();    // lcnt/s_ovn visible before any emission

    short8 aE[8], aO[8];
#pragma unroll
    for (int kt = 0; kt < 8; kt++) aE[kt] = *(const short8*)(pA + kt * 512);

    // emission: LDS-only (lgkmcnt domain); loop keeps vmcnt loads-only.
#define EMIT1(vv, q, rowl) do {                                                \
        float v = (vv);                                                        \
        if (v >= 1.984375f) {                                                  \
            int fx = (int)(v * 65536.f); if (fx > 0x7FFFF) fx = 0x7FFFF;       \
            u32 e = ((u32)(n0 + g16 * 4 + (q)) << 19) | (u32)fx;               \
            u32 off = atomicAdd(&lcnt[rowl][wave], 1u);                        \
            if (off < 2) {                                                     \
                cell[rowl][wave][off] = e;                                     \
            } else {                                                           \
                u32 p = atomicAdd(&s_ovn, 1u);                                 \
                if (p < OVCAP) { ovr[p] = rg * 512 + (rowl); ove[p] = e; }     \
            }                                                                  \
        }                                                                      \
    } while (0)

#define CHUNK(a, ch) do {                                                      \
        f32x4 ac = {0.f, 0.f, 0.f, 0.f};                                       \
        _Pragma("unroll")                                                      \
        for (int kt = 0; kt < 8; kt++)                                         \
            ac = __builtin_amdgcn_mfma_f32_16x16x32_bf16(b[kt], a[kt], ac, 0, 0, 0); \
        const int rowl = (ch) * 16 + l16;                                      \
        EMIT1(ac[0] + bqa0, 0, rowl);                                          \
        EMIT1(ac[1] + bqa1, 1, rowl);                                          \
        EMIT1(ac[2] + bqa2, 2, rowl);                                          \
        EMIT1(ac[3] + bqa3, 3, rowl);                                          \
    } while (0)

    for (int it = 0; it < 16; it++) {
        // prefetch odd chunk (loads issue before MFMA block -> hidden)
#pragma unroll
        for (int kt = 0; kt < 8; kt++) aO[kt] = *(const short8*)(pA + 4096 + kt * 512);
        CHUNK(aE, it * 2);
        // prefetch next even chunk (clamped duplicate on final iter)
        const u16* pA2 = pA + (it == 15 ? 4096 : 8192);
#pragma unroll
        for (int kt = 0; kt < 8; kt++) aE[kt] = *(const short8*)(pA2 + kt * 512);
        CHUNK(aO, it * 2 + 1);
        pA += 8192;
    }
#undef CHUNK
#undef EMIT1

    // ---- epilogue: ALL global stores happen here ---------------------------
    __syncthreads();
    // seg write: 4096 cells, 8 per thread, unconditional uint2 (0-filled)
#pragma unroll
    for (int s = 0; s < 8; s++) {
        int k = s * 512 + tid;
        int rowl = k >> 3, cw = k & 7;
        u32 nc = lcnt[rowl][cw];
        uint2 o;
        o.x = (nc > 0) ? cell[rowl][cw][0] : 0u;
        o.y = (nc > 1) ? cell[rowl][cw][1] : 0u;
        *(uint2*)(seg + ((size_t)(rg * 512 + rowl) * 512 + bx * 8 + cw) * 2) = o;
    }
    // overflow flush -> global spill lists
    u32 ovn = s_ovn;
    u32 nov = ovn < OVCAP ? ovn : OVCAP;
    for (u32 i = tid; i < nov; i += 512) {
        u32 grow = ovr[i], e = ove[i];
        u32 g = atomicAdd(&cnt[grow], 1u);
        if (g < SCAP) spill[(size_t)grow * SCAP + g] = e;
    }
    if (ovn > OVCAP) {   // never expected: poison all block rows -> exact fb
        for (int rr = tid; rr < 512; rr += 512)
            atomicAdd(&cnt[rg * 512 + rr], 1000u);
    }
}

// ---------------------------------------------------------------------------
// Kernel 2: R5-proven select (~9us): per row read 1024 seg slots (ONE
// coalesced 4 KB burst) + spills -> q-hist brackets T -> certain-in
// (z = v) / ambiguous band (fp64 refine, exact ordering) -> decode with
// bf16 W_dec. Exact streaming fallback if screen invalid (incl. poisoned
// cnt). s_sae stride-17 padded (R8: bank conflicts 2.07M -> 46K).
// XCD row-grouping: 512 contiguous rows per XCD.
// ---------------------------------------------------------------------------
__global__ __launch_bounds__(256) void select_decode(const u32* __restrict__ cnt,
                                                     const u32* __restrict__ seg,
                                                     const u32* __restrict__ spill,
                                                     const float* __restrict__ x,
                                                     const float* __restrict__ W_enc,
                                                     const float* __restrict__ b_enc,
                                                     const u16* __restrict__ Wd,
                                                     const float* __restrict__ b_dec,
                                                     float* __restrict__ out) {
    const int r    = (blockIdx.x & 7) * 512 + (blockIdx.x >> 3);   // XCD-grouped
    const int tid  = threadIdx.x;
    const int lane = tid & 63;
    const int wave = tid >> 6;
    const int grp  = tid >> 4;     // 16 groups of 16 lanes
    const int l16  = tid & 15;

    __shared__ float s_sae[272];   // stride-17 padded: idx = k + (k>>4)
    __shared__ u32   hist[256];
    __shared__ int   wtot[4];
    __shared__ int   s_t32;
    __shared__ u32   s_m, s_c1, s_namb, s_nref;
    __shared__ int   cidx[CMAX];
    __shared__ float cval[CMAX];
    __shared__ u8    csat[CMAX];
    __shared__ short ridx[RCAP];
    __shared__ float rex[RCAP];
    __shared__ float sel_val[32];
    __shared__ int   sel_idx[32];

    s_sae[tid + (tid >> 4)] = x[(size_t)r * 256 + tid] - b_dec[tid];
    hist[tid] = 0;
    if (tid == 0) { s_t32 = -1; s_m = 0; s_c1 = 0; s_namb = 0; s_nref = 0; }
    if (tid < 32) { sel_val[tid] = 0.f; sel_idx[tid] = 0; }
    __syncthreads();

    auto add_cand = [&](u32 e) {
        int fx = (int)(e & 0x7FFFFu);
        float v = (float)fx * 1.52587890625e-5f;   // /65536
        u32 p = atomicAdd(&s_m, 1u);
        if (p < CMAX) {
            cidx[p] = (int)(e >> 19);
            cval[p] = v;
            csat[p] = (fx == 0x7FFFF);
        }
        int q = (int)(v * 32.f + 0.5f); if (q > 255) q = 255;
        atomicAdd(&hist[q], 1u);
    };
    auto find_t32 = [&]() {
        int c = (int)hist[tid];
        int s = c;
#pragma unroll
        for (int off = 1; off < 64; off <<= 1) {
            int v = __shfl_down(s, off);
            if (lane + off < 64) s += v;
        }
        if (lane == 0) wtot[wave] = s;
        __syncthreads();
        int hisum = 0;
        for (int ww = wave + 1; ww < 4; ww++) hisum += wtot[ww];
        int S = s + hisum;
        if (S >= 32 && (S - c) < 32) s_t32 = tid;   // unique transition bin
        __syncthreads();
    };
    auto exact_col = [&](int col) -> double {
        const float4* wr = (const float4*)(W_enc + (size_t)col * 256 + l16 * 16);
        double s = 0.0;
#pragma unroll
        for (int u = 0; u < 4; u++) {
            float4 wv = wr[u];
            const float* sp = &s_sae[l16 * 17 + u * 4];   // padded, conflict-free
            s += (double)wv.x * (double)sp[0] + (double)wv.y * (double)sp[1]
               + (double)wv.z * (double)sp[2] + (double)wv.w * (double)sp[3];
        }
#pragma unroll
        for (int off = 8; off; off >>= 1) s += __shfl_down(s, off, 16);
        return s;
    };

    // --- gather candidates: one coalesced 4 KB burst (1024 slots/row) -------
    {
        uint4 ee = *(const uint4*)(seg + (size_t)r * 1024 + tid * 4);
        if (ee.x) add_cand(ee.x);
        if (ee.y) add_cand(ee.y);
        if (ee.z) add_cand(ee.z);
        if (ee.w) add_cand(ee.w);
    }
    const int nsp_all = (int)cnt[r];
    const int nsp = nsp_all < SCAP ? nsp_all : SCAP;
    for (int i = tid; i < nsp; i += 256)
        add_cand(spill[(size_t)r * SCAP + i]);
    __syncthreads();
    const int m = (int)s_m < CMAX ? (int)s_m : CMAX;
    find_t32();

    // t32 >= 67 <=> Tlo-2B >= 1.984 (emit screen) -> non-listed certainly out
    const bool fb_pre = (nsp_all > SCAP) || ((int)s_m > CMAX) || (s_t32 < 67);

    if (!fb_pre) {
        const float Thi = (s_t32 + 0.5f) * 0.03125f;
        const float Tlo = (s_t32 - 0.5f) * 0.03125f;
        for (int i = tid; i < m; i += 256) {
            float v = cval[i];
            if (!csat[i] && v > Thi + 2.f * BERR) {   // certainly in true top-32
                u32 p = atomicAdd(&s_c1, 1u);
                if (p < 32) { sel_val[p] = v; sel_idx[p] = cidx[i]; }
            } else if (csat[i] || v >= Tlo - 2.f * BERR) {  // ambiguous band
                u32 p = atomicAdd(&s_namb, 1u);
                if (p < RCAP) ridx[p] = (short)i;
            }
        }
    }
    __syncthreads();
    const int c1 = (int)s_c1, namb = (int)s_namb;
    const bool fb = fb_pre || (namb > RCAP) || (c1 > 31);

    if (!fb) {
        // --- fp64 refine of ambiguous band: 2 per 16-lane group per pass ----
        for (int t0 = 0; t0 < namb; t0 += 32) {
            int cA = t0 + grp, cB = t0 + grp + 16;
            if (cA < namb) {
                int iA = cidx[ridx[cA]];
                double s = exact_col(iA);
                if (l16 == 0) {
                    float f = (float)(s + (double)b_enc[iA]);
                    rex[cA] = f > 0.f ? f : 0.f;
                }
            }
            if (cB < namb) {
                int iB = cidx[ridx[cB]];
                double s = exact_col(iB);
                if (l16 == 0) {
                    float f = (float)(s + (double)b_enc[iB]);
                    rex[cB] = f > 0.f ? f : 0.f;
                }
            }
        }
        __syncthreads();

        // --- top (32-c1) of band by (exact desc, idx asc) --------------------
        const int need = 32 - c1;
        for (int k = tid; k < namb; k += 256) {
            float vi = rex[k];
            int   ii = cidx[ridx[k]];
            int rank = 0;
            for (int j = 0; j < namb; j++) {
                float vj = rex[j];
                rank += (vj > vi) || (vj == vi && cidx[ridx[j]] < ii);
            }
            if (rank < need) { sel_val[c1 + rank] = vi; sel_idx[c1 + rank] = ii; }
        }
        __syncthreads();
    } else {
        // --- exact streaming fallback over all 8192 cols (never expected) ---
        hist[tid] = 0;
        if (tid == 0) { s_t32 = -1; s_nref = 0; }
        __syncthreads();
        for (int it = 0; it < 512; it++) {
            int col = it * 16 + grp;
            double s = exact_col(col);
            if (l16 == 0) {
                float f = (float)(s + (double)b_enc[col]);
                f = f > 0.f ? f : 0.f;
                int q = (int)(f * 32.f + 0.5f); if (q > 255) q = 255;
                if (q >= 1) atomicAdd(&hist[q], 1u);
            }
        }
        __syncthreads();
        find_t32();
        int qlo = s_t32 >= 3 ? s_t32 - 2 : 1;
        for (int pass = 0; pass < 2; pass++) {
            for (int it = 0; it < 512; it++) {
                int col = it * 16 + grp;
                double s = exact_col(col);
                if (l16 == 0) {
                    float f = (float)(s + (double)b_enc[col]);
                    f = f > 0.f ? f : 0.f;
                    int q = (int)(f * 32.f + 0.5f); if (q > 255) q = 255;
                    if (q >= qlo) {
                        u32 p = atomicAdd(&s_nref, 1u);
                        if (p < CMAX) { cidx[p] = col; cval[p] = f; }
                    }
                }
            }
            __syncthreads();
            if ((int)s_nref <= CMAX) break;
            if (tid == 0) s_nref = 0;
            qlo = s_t32 > 0 ? s_t32 : 1;
            __syncthreads();
        }
        int nf = (int)s_nref; if (nf > CMAX) nf = CMAX;
        for (int k = tid; k < nf; k += 256) {
            float vi = cval[k]; int ii = cidx[k]; int rank = 0;
            for (int j = 0; j < nf; j++)
                rank += (cval[j] > vi) || (cval[j] == vi && cidx[j] < ii);
            if (rank < 32) { sel_val[rank] = vi; sel_idx[rank] = ii; }
        }
        __syncthreads();
    }

    // --- decode: out[r] = b_dec + sum_k z_k * bf16(W_dec)[idx_k] ------------
    u16 wv[32];
#pragma unroll
    for (int k = 0; k < 32; k++)
        wv[k] = Wd[(size_t)sel_idx[k] * 256 + tid];   // 32 independent loads
    float acc = b_dec[tid];
#pragma unroll
    for (int k = 0; k < 32; k++)
        acc += sel_val[k] * bf2f(wv[k]);
    out[(size_t)r * 256 + tid] = acc;
}

// ---------------------------------------------------------------------------
// ws layout (~27.5 MB; ws_size 256 MB):
//   cnt 16 KB | seg 16 MB (seg[4096][512][2] u32, fully written by encode) |
//   spill 1.5 MB | Ap 2 MB | Wb 4 MB | Wd 4 MB
// ---------------------------------------------------------------------------
extern "C" void kernel_launch(void* const* d_in, const int* in_sizes, int n_in,
                              void* d_out, int out_size, void* d_ws, size_t ws_size,
                              hipStream_t stream) {
    const float* x     = (const float*)d_in[0];   // [4096,256] f32
    const float* W_enc = (const float*)d_in[1];   // [8192,256] f32
    const float* b_enc = (const float*)d_in[2];   // [8192]     f32
    const float* W_dec = (const float*)d_in[3];   // [8192,256] f32
    const float* b_dec = (const float*)d_in[4];   // [256]      f32
    float* out = (float*)d_out;                   // [4096,256] f32

    u32* cnt   = (u32*)d_ws;                            // 16 KB spill counters
    u32* seg   = cnt + 4096;                            // 16 MB candidate cells
    u32* spill = seg + (size_t)4096 * 1024;             // 1.5 MB spill lists
    u16* Ap    = (u16*)(spill + (size_t)4096 * SCAP);   // 2 MB swizzled bf16(x-b_dec)
    u16* Wb    = Ap + (size_t)4096 * 256;               // 4 MB swizzled bf16(W_enc)
    u16* Wd    = Wb + (size_t)8192 * 256;               // 4 MB bf16(W_dec)

    prep_convert<<<2576, 256, 0, stream>>>(x, b_dec, W_enc, W_dec, Ap, Wb, Wd, cnt);
    encode_gemm<<<512, 512, 0, stream>>>(Ap, Wb, b_enc, cnt, seg, spill);
    select_decode<<<4096, 256, 0, stream>>>(cnt, seg, spill, x, W_enc, b_enc, Wd, b_dec, out);
}